// Round 1
// baseline (699.876 us; speedup 1.0000x reference)
//
#include <hip/hip_runtime.h>
#include <math.h>

#define HID 128

static __device__ __forceinline__ float eluf(float x){ return x > 0.f ? x : expm1f(x); }

__global__ __launch_bounds__(256) void k_hist(const int* __restrict__ dst, int* __restrict__ deg, int E){
  int e = blockIdx.x*256 + threadIdx.x;
  if (e < E) atomicAdd(&deg[dst[e]], 1);
}

// per-block exclusive scan over 1024 elements (256 thr x 4), emits block sums
__global__ __launch_bounds__(256) void k_scan_local(const int* __restrict__ deg, int* __restrict__ excl,
                                                    int* __restrict__ bsums, int n){
  __shared__ int ts[256];
  int t = threadIdx.x;
  int base = blockIdx.x*1024;
  int v[4]; int s = 0;
  #pragma unroll
  for (int j=0;j<4;j++){ int i = base + t*4 + j; v[j] = (i<n)?deg[i]:0; s += v[j]; }
  ts[t]=s; __syncthreads();
  for (int off=1; off<256; off<<=1){
    int x = (t>=off)?ts[t-off]:0; __syncthreads();
    ts[t]+=x; __syncthreads();
  }
  int excl_t = ts[t]-s;
  if (t==255) bsums[blockIdx.x]=ts[255];
  int run = excl_t;
  #pragma unroll
  for (int j=0;j<4;j++){ int i = base+t*4+j; if (i<n) excl[i]=run; run+=v[j]; }
}

__global__ void k_scan_bsums(int* bsums, int nb){
  int run=0;
  for (int i=0;i<nb;i++){ int x=bsums[i]; bsums[i]=run; run+=x; }
}

__global__ __launch_bounds__(256) void k_finalize(const int* __restrict__ deg, int* __restrict__ rowptr,
                                                  const int* __restrict__ bsums, int* __restrict__ cursor,
                                                  float* __restrict__ dinv, int n){
  int i = blockIdx.x*256+threadIdx.x;
  if (i<n){
    int r = rowptr[i] + bsums[i>>10];
    rowptr[i]=r; cursor[i]=r;
    dinv[i] = rsqrtf((float)deg[i] + 1.0f);
  }
}

__global__ __launch_bounds__(256) void k_fill(const int* __restrict__ src, const int* __restrict__ dst,
                                              int* __restrict__ cursor, const float* __restrict__ dinv,
                                              int* __restrict__ csrc, float* __restrict__ cw, int E){
  int e = blockIdx.x*256+threadIdx.x;
  if (e<E){
    int s = src[e], d = dst[e];
    int p = atomicAdd(&cursor[d],1);
    csrc[p]=s; cw[p]=dinv[s]*dinv[d];
  }
}

__global__ __launch_bounds__(256) void k_init_acc(const float* __restrict__ emb, const int* __restrict__ xidx,
                                                  float* __restrict__ acc, int n){
  int i = blockIdx.x*256+threadIdx.x;
  int total = n*32;
  if (i<total){
    int nn = i>>5, q = i&31;
    ((float4*)acc)[i] = ((const float4*)emb)[xidx[nn]*32+q];
  }
}

// 64-node x 128-out tile; 256 thr; each thread: 8 nodes x 4 cols (x2 matrices if DUAL).
// DUAL: O0 = A@W0 (xw); O1 = A@W1 + b0 + b1 + O0*dinv^2 (pre-fused "base")
// !DUAL: O0 = elu(A@W0 + b0)
template<bool DUAL>
__global__ __launch_bounds__(256) void k_gemm(
    const float* __restrict__ A, const float* __restrict__ W0, const float* __restrict__ W1,
    const float* __restrict__ b0, const float* __restrict__ b1, const float* __restrict__ dinv,
    float* __restrict__ O0, float* __restrict__ O1, int n)
{
  __shared__ float As[64][36];
  __shared__ float Ws0[32][128];
  __shared__ float Ws1[DUAL?32:1][128];
  int tid = threadIdx.x;
  int tcol = tid & 31, trow = tid >> 5;
  int n0 = blockIdx.x*64;
  float aC[8][4]; float aL[8][4];
  #pragma unroll
  for (int i=0;i<8;i++){
    #pragma unroll
    for (int c=0;c<4;c++){ aC[i][c]=0.f; if(DUAL) aL[i][c]=0.f; }
  }

  for (int k0=0;k0<HID;k0+=32){
    for (int f=tid; f<512; f+=256){
      int r = f>>3, c4 = f&7;
      int gn = n0+r;
      float4 v = make_float4(0.f,0.f,0.f,0.f);
      if (gn<n) v = *(const float4*)&A[gn*HID + k0 + c4*4];
      *(float4*)&As[r][c4*4] = v;
    }
    for (int j=0;j<4;j++){
      int f = tid + j*256;
      int r = f>>5, c4 = f&31;
      *(float4*)&Ws0[r][c4*4] = *(const float4*)&W0[(k0+r)*HID + c4*4];
      if (DUAL) *(float4*)&Ws1[r][c4*4] = *(const float4*)&W1[(k0+r)*HID + c4*4];
    }
    __syncthreads();
    #pragma unroll 4
    for (int kk=0;kk<32;kk++){
      float4 w0 = *(const float4*)&Ws0[kk][tcol*4];
      float4 w1 = make_float4(0.f,0.f,0.f,0.f);
      if (DUAL) w1 = *(const float4*)&Ws1[kk][tcol*4];
      #pragma unroll
      for (int i=0;i<8;i++){
        float a = As[trow*8+i][kk];
        aC[i][0] += a*w0.x; aC[i][1] += a*w0.y; aC[i][2] += a*w0.z; aC[i][3] += a*w0.w;
        if (DUAL){ aL[i][0]+=a*w1.x; aL[i][1]+=a*w1.y; aL[i][2]+=a*w1.z; aL[i][3]+=a*w1.w; }
      }
    }
    __syncthreads();
  }
  float4 bb0 = *(const float4*)&b0[tcol*4];
  float4 bb1 = make_float4(0.f,0.f,0.f,0.f);
  if (DUAL) bb1 = *(const float4*)&b1[tcol*4];
  #pragma unroll
  for (int i=0;i<8;i++){
    int gn = n0 + trow*8 + i;
    if (gn >= n) continue;
    if (DUAL){
      float dn = dinv[gn]; float snm = dn*dn;
      float4 xc; xc.x=aC[i][0]; xc.y=aC[i][1]; xc.z=aC[i][2]; xc.w=aC[i][3];
      *(float4*)&O0[gn*HID + tcol*4] = xc;
      float4 bs;
      bs.x = aL[i][0] + bb0.x + bb1.x + xc.x*snm;
      bs.y = aL[i][1] + bb0.y + bb1.y + xc.y*snm;
      bs.z = aL[i][2] + bb0.z + bb1.z + xc.z*snm;
      bs.w = aL[i][3] + bb0.w + bb1.w + xc.w*snm;
      *(float4*)&O1[gn*HID + tcol*4] = bs;
    } else {
      float4 xo;
      xo.x = eluf(aC[i][0] + bb0.x);
      xo.y = eluf(aC[i][1] + bb0.y);
      xo.z = eluf(aC[i][2] + bb0.z);
      xo.w = eluf(aC[i][3] + bb0.w);
      *(float4*)&O0[gn*HID + tcol*4] = xo;
    }
  }
}

// one wave per node: gather xw rows of in-neighbors, fuse elu + residual acc update
__global__ __launch_bounds__(256) void k_agg(const float* __restrict__ xw, const float* __restrict__ base,
    float* __restrict__ acc, const int* __restrict__ rowptr, const int* __restrict__ rowend,
    const int* __restrict__ csrc, const float* __restrict__ cw, int n)
{
  int wid = threadIdx.x>>6, lane = threadIdx.x & 63;
  int node = blockIdx.x*4 + wid;
  if (node>=n) return;
  int s = rowptr[node], e = rowend[node];
  float s0=0.f, s1=0.f;
  for (int p=s;p<e;p++){
    int u = csrc[p]; float w = cw[p];
    float2 v = *(const float2*)&xw[u*HID + lane*2];
    s0 += w*v.x; s1 += w*v.y;
  }
  float2 b = *(const float2*)&base[node*HID + lane*2];
  float x0 = eluf(b.x + s0), x1 = eluf(b.y + s1);
  float2 a = *(float2*)&acc[node*HID + lane*2];
  a.x += x0; a.y += x1;
  *(float2*)&acc[node*HID + lane*2] = a;
}

static __device__ __forceinline__ int lowerb(const int* a, int nn, int key){
  int lo=0, hi=nn;
  while (lo<hi){ int m=(lo+hi)>>1; if (a[m]<key) lo=m+1; else hi=m; }
  return lo;
}

__global__ __launch_bounds__(128) void k_pool(const float* __restrict__ x, const int* __restrict__ batch,
                                              float* __restrict__ pooled, int n, int G){
  int g = blockIdx.x; int d = threadIdx.x;
  int s = lowerb(batch, n, g), e = lowerb(batch, n, g+1);
  float sum=0.f;
  for (int nn=s; nn<e; nn++) sum += x[nn*HID + d];
  pooled[g*HID+d]=sum;
}

__global__ __launch_bounds__(128) void k_pred(const float* __restrict__ pooled, const float* __restrict__ W,
                                              const float* __restrict__ b, float* __restrict__ out, int G){
  __shared__ float pr[HID];
  int g = blockIdx.x, o = threadIdx.x;
  pr[o] = pooled[g*HID+o];
  __syncthreads();
  float s = b[o];
  #pragma unroll 8
  for (int k=0;k<HID;k++) s += pr[k]*W[k*HID+o];
  out[g*HID+o] = s*0.1f;
}

extern "C" void kernel_launch(void* const* d_in, const int* in_sizes, int n_in,
                              void* d_out, int out_size, void* d_ws, size_t ws_size,
                              hipStream_t stream)
{
  const int*   x_idx  = (const int*)d_in[0];
  const int*   eidx   = (const int*)d_in[1];
  const int*   batch  = (const int*)d_in[2];
  const float* emb    = (const float*)d_in[3];
  const float* convW  = (const float*)d_in[4];
  const float* convb  = (const float*)d_in[5];
  const float* linW   = (const float*)d_in[6];
  const float* linb   = (const float*)d_in[7];
  const float* mlpW   = (const float*)d_in[8];
  const float* mlpb   = (const float*)d_in[9];
  const float* predW  = (const float*)d_in[10];
  const float* predb  = (const float*)d_in[11];
  float* out = (float*)d_out;
  int N = in_sizes[0];
  int E = in_sizes[1]/2;
  int G = out_size / 128;   // OUT = 128

  char* p = (char*)d_ws;
  auto alloc = [&](size_t bytes)->char*{ char* q = p; p += (bytes + 255) & ~(size_t)255; return q; };
  int*   deg    = (int*)  alloc((size_t)N*4);
  int*   rowptr = (int*)  alloc((size_t)N*4);
  int*   cursor = (int*)  alloc((size_t)N*4);
  int*   bsums  = (int*)  alloc(4096);
  float* dinv   = (float*)alloc((size_t)N*4);
  int*   csrc   = (int*)  alloc((size_t)E*4);
  float* cw     = (float*)alloc((size_t)E*4);
  float* acc    = (float*)alloc((size_t)N*HID*4);
  float* xw     = (float*)alloc((size_t)N*HID*4);
  float* basev  = (float*)alloc((size_t)N*HID*4);
  float* pooled = (float*)alloc((size_t)G*HID*4);
  if ((size_t)(p - (char*)d_ws) > ws_size) return; // ws too small: leave poison -> loud failure

  const int* src = eidx;
  const int* dst = eidx + E;

  hipMemsetAsync(deg, 0, (size_t)N*4, stream);
  k_hist<<<(E+255)/256,256,0,stream>>>(dst, deg, E);
  int nb = (N+1023)/1024;
  k_scan_local<<<nb,256,0,stream>>>(deg, rowptr, bsums, N);
  k_scan_bsums<<<1,1,0,stream>>>(bsums, nb);
  k_finalize<<<(N+255)/256,256,0,stream>>>(deg, rowptr, bsums, cursor, dinv, N);
  k_fill<<<(E+255)/256,256,0,stream>>>(src, dst, cursor, dinv, csrc, cw, E);
  k_init_acc<<<(N*32+255)/256,256,0,stream>>>(emb, x_idx, acc, N);

  int gblk = (N+63)/64;
  for (int l=0;l<3;l++){
    k_gemm<true><<<gblk,256,0,stream>>>(acc, convW + (size_t)l*HID*HID, linW + (size_t)l*HID*HID,
                                        convb + l*HID, linb + l*HID, dinv, xw, basev, N);
    k_agg<<<(N+3)/4,256,0,stream>>>(xw, basev, acc, rowptr, cursor, csrc, cw, N);
  }
  k_gemm<false><<<gblk,256,0,stream>>>(acc, mlpW, nullptr, mlpb, nullptr, nullptr, xw, nullptr, N);
  k_pool<<<G,128,0,stream>>>(xw, batch, pooled, N, G);
  k_pred<<<G,128,0,stream>>>(pooled, predW, predb, out, G);
}

// Round 3
// 597.587 us; speedup vs baseline: 1.1712x; 1.1712x over previous
//
#include <hip/hip_runtime.h>
#include <math.h>

#define HID 128
#define POOL_S 8

static __device__ __forceinline__ float eluf(float x){ return x > 0.f ? x : expm1f(x); }

__global__ __launch_bounds__(256) void k_hist(const int* __restrict__ dst, int* __restrict__ deg, int E){
  int e = blockIdx.x*256 + threadIdx.x;
  if (e < E) atomicAdd(&deg[dst[e]], 1);
}

// per-block exclusive scan over 1024 elements (256 thr x 4), emits block sums
__global__ __launch_bounds__(256) void k_scan_local(const int* __restrict__ deg, int* __restrict__ excl,
                                                    int* __restrict__ bsums, int n){
  __shared__ int ts[256];
  int t = threadIdx.x;
  int base = blockIdx.x*1024;
  int v[4]; int s = 0;
  #pragma unroll
  for (int j=0;j<4;j++){ int i = base + t*4 + j; v[j] = (i<n)?deg[i]:0; s += v[j]; }
  ts[t]=s; __syncthreads();
  for (int off=1; off<256; off<<=1){
    int x = (t>=off)?ts[t-off]:0; __syncthreads();
    ts[t]+=x; __syncthreads();
  }
  int excl_t = ts[t]-s;
  if (t==255) bsums[blockIdx.x]=ts[255];
  int run = excl_t;
  #pragma unroll
  for (int j=0;j<4;j++){ int i = base+t*4+j; if (i<n) excl[i]=run; run+=v[j]; }
}

__global__ void k_scan_bsums(int* bsums, int nb){
  int run=0;
  for (int i=0;i<nb;i++){ int x=bsums[i]; bsums[i]=run; run+=x; }
}

__global__ __launch_bounds__(256) void k_finalize(const int* __restrict__ deg, int* __restrict__ rowptr,
                                                  const int* __restrict__ bsums, int* __restrict__ cursor,
                                                  float* __restrict__ dinv, int n){
  int i = blockIdx.x*256+threadIdx.x;
  if (i<n){
    int r = rowptr[i] + bsums[i>>10];
    rowptr[i]=r; cursor[i]=r;
    dinv[i] = rsqrtf((float)deg[i] + 1.0f);
  }
}

__global__ __launch_bounds__(256) void k_fill(const int* __restrict__ src, const int* __restrict__ dst,
                                              int* __restrict__ cursor, const float* __restrict__ dinv,
                                              int* __restrict__ csrc, float* __restrict__ cw, int E){
  int e = blockIdx.x*256+threadIdx.x;
  if (e<E){
    int s = src[e], d = dst[e];
    int p = atomicAdd(&cursor[d],1);
    csrc[p]=s; cw[p]=dinv[s]*dinv[d];
  }
}

__global__ __launch_bounds__(256) void k_init_acc(const float* __restrict__ emb, const int* __restrict__ xidx,
                                                  float* __restrict__ acc, int n){
  int i = blockIdx.x*256+threadIdx.x;
  int total = n*32;
  if (i<total){
    int nn = i>>5, q = i&31;
    ((float4*)acc)[i] = ((const float4*)emb)[xidx[nn]*32+q];
  }
}

// 64-node x 128-out tile; 256 thr; each thread: 8 nodes x 4 cols (x2 matrices if DUAL).
// DUAL: O0 = A@W0 (xw); O1 = A@W1 + b0 + b1 + O0*dinv^2 (pre-fused "base")
// !DUAL: O0 = elu(A@W0 + b0)
template<bool DUAL>
__global__ __launch_bounds__(256) void k_gemm(
    const float* __restrict__ A, const float* __restrict__ W0, const float* __restrict__ W1,
    const float* __restrict__ b0, const float* __restrict__ b1, const float* __restrict__ dinv,
    float* __restrict__ O0, float* __restrict__ O1, int n)
{
  __shared__ float As[64][36];
  __shared__ float Ws0[32][128];
  __shared__ float Ws1[DUAL?32:1][128];
  int tid = threadIdx.x;
  int tcol = tid & 31, trow = tid >> 5;
  int n0 = blockIdx.x*64;
  float aC[8][4]; float aL[8][4];
  #pragma unroll
  for (int i=0;i<8;i++){
    #pragma unroll
    for (int c=0;c<4;c++){ aC[i][c]=0.f; if(DUAL) aL[i][c]=0.f; }
  }

  for (int k0=0;k0<HID;k0+=32){
    for (int f=tid; f<512; f+=256){
      int r = f>>3, c4 = f&7;
      int gn = n0+r;
      float4 v = make_float4(0.f,0.f,0.f,0.f);
      if (gn<n) v = *(const float4*)&A[gn*HID + k0 + c4*4];
      *(float4*)&As[r][c4*4] = v;
    }
    for (int j=0;j<4;j++){
      int f = tid + j*256;
      int r = f>>5, c4 = f&31;
      *(float4*)&Ws0[r][c4*4] = *(const float4*)&W0[(k0+r)*HID + c4*4];
      if (DUAL) *(float4*)&Ws1[r][c4*4] = *(const float4*)&W1[(k0+r)*HID + c4*4];
    }
    __syncthreads();
    #pragma unroll 4
    for (int kk=0;kk<32;kk++){
      float4 w0 = *(const float4*)&Ws0[kk][tcol*4];
      float4 w1 = make_float4(0.f,0.f,0.f,0.f);
      if (DUAL) w1 = *(const float4*)&Ws1[kk][tcol*4];
      #pragma unroll
      for (int i=0;i<8;i++){
        float a = As[trow*8+i][kk];
        aC[i][0] += a*w0.x; aC[i][1] += a*w0.y; aC[i][2] += a*w0.z; aC[i][3] += a*w0.w;
        if (DUAL){ aL[i][0]+=a*w1.x; aL[i][1]+=a*w1.y; aL[i][2]+=a*w1.z; aL[i][3]+=a*w1.w; }
      }
    }
    __syncthreads();
  }
  float4 bb0 = *(const float4*)&b0[tcol*4];
  float4 bb1 = make_float4(0.f,0.f,0.f,0.f);
  if (DUAL) bb1 = *(const float4*)&b1[tcol*4];
  #pragma unroll
  for (int i=0;i<8;i++){
    int gn = n0 + trow*8 + i;
    if (gn >= n) continue;
    if (DUAL){
      float dn = dinv[gn]; float snm = dn*dn;
      float4 xc; xc.x=aC[i][0]; xc.y=aC[i][1]; xc.z=aC[i][2]; xc.w=aC[i][3];
      *(float4*)&O0[gn*HID + tcol*4] = xc;
      float4 bs;
      bs.x = aL[i][0] + bb0.x + bb1.x + xc.x*snm;
      bs.y = aL[i][1] + bb0.y + bb1.y + xc.y*snm;
      bs.z = aL[i][2] + bb0.z + bb1.z + xc.z*snm;
      bs.w = aL[i][3] + bb0.w + bb1.w + xc.w*snm;
      *(float4*)&O1[gn*HID + tcol*4] = bs;
    } else {
      float4 xo;
      xo.x = eluf(aC[i][0] + bb0.x);
      xo.y = eluf(aC[i][1] + bb0.y);
      xo.z = eluf(aC[i][2] + bb0.z);
      xo.w = eluf(aC[i][3] + bb0.w);
      *(float4*)&O0[gn*HID + tcol*4] = xo;
    }
  }
}

// one wave per node: gather xw rows of in-neighbors, fuse elu + residual acc update
__global__ __launch_bounds__(256) void k_agg(const float* __restrict__ xw, const float* __restrict__ base,
    float* __restrict__ acc, const int* __restrict__ rowptr, const int* __restrict__ rowend,
    const int* __restrict__ csrc, const float* __restrict__ cw, int n)
{
  int wid = threadIdx.x>>6, lane = threadIdx.x & 63;
  int node = blockIdx.x*4 + wid;
  if (node>=n) return;
  int s = rowptr[node], e = rowend[node];
  float s0=0.f, s1=0.f;
  for (int p=s;p<e;p++){
    int u = csrc[p]; float w = cw[p];
    float2 v = *(const float2*)&xw[u*HID + lane*2];
    s0 += w*v.x; s1 += w*v.y;
  }
  float2 b = *(const float2*)&base[node*HID + lane*2];
  float x0 = eluf(b.x + s0), x1 = eluf(b.y + s1);
  float2 a = *(float2*)&acc[node*HID + lane*2];
  a.x += x0; a.y += x1;
  *(float2*)&acc[node*HID + lane*2] = a;
}

static __device__ __forceinline__ int lowerb(const int* a, int nn, int key){
  int lo=0, hi=nn;
  while (lo<hi){ int m=(lo+hi)>>1; if (a[m]<key) lo=m+1; else hi=m; }
  return lo;
}

// deterministic 2-stage pooling, stage 1: G*POOL_S blocks, fixed row partition
__global__ __launch_bounds__(128) void k_pool_part(const float* __restrict__ x, const int* __restrict__ batch,
                                                   float* __restrict__ part, int n){
  int g = blockIdx.x / POOL_S, s = blockIdx.x % POOL_S;
  int d = threadIdx.x;
  int lo = lowerb(batch, n, g), hi = lowerb(batch, n, g+1);
  float sum = 0.f;
  for (int r = lo + s; r < hi; r += POOL_S) sum += x[r*HID + d];
  part[blockIdx.x*HID + d] = sum;
}

// stage 2 fused into pred: fixed-order reduce of POOL_S partials, then GEMV
__global__ __launch_bounds__(128) void k_pred(const float* __restrict__ part, const float* __restrict__ W,
                                              const float* __restrict__ b, float* __restrict__ out, int G){
  __shared__ float pr[HID];
  int g = blockIdx.x, o = threadIdx.x;
  float s = 0.f;
  #pragma unroll
  for (int q=0;q<POOL_S;q++) s += part[(g*POOL_S+q)*HID + o];
  pr[o] = s;
  __syncthreads();
  float acc = b[o];
  #pragma unroll 8
  for (int k=0;k<HID;k++) acc += pr[k]*W[k*HID+o];
  out[g*HID+o] = acc*0.1f;
}

extern "C" void kernel_launch(void* const* d_in, const int* in_sizes, int n_in,
                              void* d_out, int out_size, void* d_ws, size_t ws_size,
                              hipStream_t stream)
{
  const int*   x_idx  = (const int*)d_in[0];
  const int*   eidx   = (const int*)d_in[1];
  const int*   batch  = (const int*)d_in[2];
  const float* emb    = (const float*)d_in[3];
  const float* convW  = (const float*)d_in[4];
  const float* convb  = (const float*)d_in[5];
  const float* linW   = (const float*)d_in[6];
  const float* linb   = (const float*)d_in[7];
  const float* mlpW   = (const float*)d_in[8];
  const float* mlpb   = (const float*)d_in[9];
  const float* predW  = (const float*)d_in[10];
  const float* predb  = (const float*)d_in[11];
  float* out = (float*)d_out;
  int N = in_sizes[0];
  int E = in_sizes[1]/2;
  int G = out_size / 128;   // OUT = 128

  char* p = (char*)d_ws;
  auto alloc = [&](size_t bytes)->char*{ char* q = p; p += (bytes + 255) & ~(size_t)255; return q; };
  int*   deg    = (int*)  alloc((size_t)N*4);
  int*   rowptr = (int*)  alloc((size_t)N*4);
  int*   cursor = (int*)  alloc((size_t)N*4);
  int*   bsums  = (int*)  alloc(4096);
  float* dinv   = (float*)alloc((size_t)N*4);
  int*   csrc   = (int*)  alloc((size_t)E*4);
  float* cw     = (float*)alloc((size_t)E*4);
  float* acc    = (float*)alloc((size_t)N*HID*4);
  float* xw     = (float*)alloc((size_t)N*HID*4);
  float* basev  = (float*)alloc((size_t)N*HID*4);
  float* part   = (float*)alloc((size_t)G*POOL_S*HID*4);
  if ((size_t)(p - (char*)d_ws) > ws_size) return; // ws too small: leave poison -> loud failure

  const int* src = eidx;
  const int* dst = eidx + E;

  hipMemsetAsync(deg, 0, (size_t)N*4, stream);
  k_hist<<<(E+255)/256,256,0,stream>>>(dst, deg, E);
  int nb = (N+1023)/1024;
  k_scan_local<<<nb,256,0,stream>>>(deg, rowptr, bsums, N);
  k_scan_bsums<<<1,1,0,stream>>>(bsums, nb);
  k_finalize<<<(N+255)/256,256,0,stream>>>(deg, rowptr, bsums, cursor, dinv, N);
  k_fill<<<(E+255)/256,256,0,stream>>>(src, dst, cursor, dinv, csrc, cw, E);
  k_init_acc<<<(N*32+255)/256,256,0,stream>>>(emb, x_idx, acc, N);

  int gblk = (N+63)/64;
  for (int l=0;l<3;l++){
    k_gemm<true><<<gblk,256,0,stream>>>(acc, convW + (size_t)l*HID*HID, linW + (size_t)l*HID*HID,
                                        convb + l*HID, linb + l*HID, dinv, xw, basev, N);
    k_agg<<<(N+3)/4,256,0,stream>>>(xw, basev, acc, rowptr, cursor, csrc, cw, N);
  }
  k_gemm<false><<<gblk,256,0,stream>>>(acc, mlpW, nullptr, mlpb, nullptr, nullptr, xw, nullptr, N);
  k_pool_part<<<G*POOL_S,128,0,stream>>>(xw, batch, part, N);
  k_pred<<<G,128,0,stream>>>(part, predW, predb, out, G);
}

// Round 4
// 448.915 us; speedup vs baseline: 1.5590x; 1.3312x over previous
//
#include <hip/hip_runtime.h>
#include <math.h>

#define HID 128
#define POOL_S 8

static __device__ __forceinline__ float eluf(float x){ return x > 0.f ? x : expm1f(x); }

// round-to-nearest-even f32 -> bf16 bits
static __device__ __forceinline__ unsigned short f2bf(float f){
  unsigned u = __builtin_bit_cast(unsigned, f);
  u += 0x7fffu + ((u >> 16) & 1u);
  return (unsigned short)(u >> 16);
}
static __device__ __forceinline__ float bflo(unsigned u){ return __builtin_bit_cast(float, u << 16); }
static __device__ __forceinline__ float bfhi(unsigned u){ return __builtin_bit_cast(float, u & 0xffff0000u); }

__global__ __launch_bounds__(256) void k_hist(const int* __restrict__ dst, int* __restrict__ deg, int E){
  int e = blockIdx.x*256 + threadIdx.x;
  if (e < E) atomicAdd(&deg[dst[e]], 1);
}

// per-block exclusive scan over 1024 elements (256 thr x 4), emits block sums
__global__ __launch_bounds__(256) void k_scan_local(const int* __restrict__ deg, int* __restrict__ excl,
                                                    int* __restrict__ bsums, int n){
  __shared__ int ts[256];
  int t = threadIdx.x;
  int base = blockIdx.x*1024;
  int v[4]; int s = 0;
  #pragma unroll
  for (int j=0;j<4;j++){ int i = base + t*4 + j; v[j] = (i<n)?deg[i]:0; s += v[j]; }
  ts[t]=s; __syncthreads();
  for (int off=1; off<256; off<<=1){
    int x = (t>=off)?ts[t-off]:0; __syncthreads();
    ts[t]+=x; __syncthreads();
  }
  int excl_t = ts[t]-s;
  if (t==255) bsums[blockIdx.x]=ts[255];
  int run = excl_t;
  #pragma unroll
  for (int j=0;j<4;j++){ int i = base+t*4+j; if (i<n) excl[i]=run; run+=v[j]; }
}

__global__ void k_scan_bsums(int* bsums, int nb){
  int run=0;
  for (int i=0;i<nb;i++){ int x=bsums[i]; bsums[i]=run; run+=x; }
}

__global__ __launch_bounds__(256) void k_finalize(const int* __restrict__ deg, int* __restrict__ rowptr,
                                                  const int* __restrict__ bsums, int* __restrict__ cursor,
                                                  float* __restrict__ dinv, int n){
  int i = blockIdx.x*256+threadIdx.x;
  if (i<n){
    int r = rowptr[i] + bsums[i>>10];
    rowptr[i]=r; cursor[i]=r;
    dinv[i] = rsqrtf((float)deg[i] + 1.0f);
  }
}

__global__ __launch_bounds__(256) void k_fill(const int* __restrict__ src, const int* __restrict__ dst,
                                              int* __restrict__ cursor, const float* __restrict__ dinv,
                                              int* __restrict__ csrc, float* __restrict__ cw, int E){
  int e = blockIdx.x*256+threadIdx.x;
  if (e<E){
    int s = src[e], d = dst[e];
    int p = atomicAdd(&cursor[d],1);
    csrc[p]=s; cw[p]=dinv[s]*dinv[d];
  }
}

__global__ __launch_bounds__(256) void k_init_acc(const float* __restrict__ emb, const int* __restrict__ xidx,
                                                  float* __restrict__ acc, int n){
  int i = blockIdx.x*256+threadIdx.x;
  int total = n*32;
  if (i<total){
    int nn = i>>5, q = i&31;
    ((float4*)acc)[i] = ((const float4*)emb)[xidx[nn]*32+q];
  }
}

// 64-node x 128-out tile; 256 thr; each thread: 8 nodes x 4 cols (x2 matrices if DUAL).
// DUAL: O0b = bf16(A@W0) (xw for gather); O1 = A@W1 + b0 + b1 + (A@W0)*dinv^2 (fp32 "base")
// !DUAL: O0f = elu(A@W0 + b0)  (fp32)
template<bool DUAL>
__global__ __launch_bounds__(256) void k_gemm(
    const float* __restrict__ A, const float* __restrict__ W0, const float* __restrict__ W1,
    const float* __restrict__ b0, const float* __restrict__ b1, const float* __restrict__ dinv,
    unsigned short* __restrict__ O0b, float* __restrict__ O0f, float* __restrict__ O1, int n)
{
  __shared__ float As[64][36];
  __shared__ float Ws0[32][128];
  __shared__ float Ws1[DUAL?32:1][128];
  int tid = threadIdx.x;
  int tcol = tid & 31, trow = tid >> 5;
  int n0 = blockIdx.x*64;
  float aC[8][4]; float aL[8][4];
  #pragma unroll
  for (int i=0;i<8;i++){
    #pragma unroll
    for (int c=0;c<4;c++){ aC[i][c]=0.f; if(DUAL) aL[i][c]=0.f; }
  }

  for (int k0=0;k0<HID;k0+=32){
    for (int f=tid; f<512; f+=256){
      int r = f>>3, c4 = f&7;
      int gn = n0+r;
      float4 v = make_float4(0.f,0.f,0.f,0.f);
      if (gn<n) v = *(const float4*)&A[gn*HID + k0 + c4*4];
      *(float4*)&As[r][c4*4] = v;
    }
    for (int j=0;j<4;j++){
      int f = tid + j*256;
      int r = f>>5, c4 = f&31;
      *(float4*)&Ws0[r][c4*4] = *(const float4*)&W0[(k0+r)*HID + c4*4];
      if (DUAL) *(float4*)&Ws1[r][c4*4] = *(const float4*)&W1[(k0+r)*HID + c4*4];
    }
    __syncthreads();
    #pragma unroll 4
    for (int kk=0;kk<32;kk++){
      float4 w0 = *(const float4*)&Ws0[kk][tcol*4];
      float4 w1 = make_float4(0.f,0.f,0.f,0.f);
      if (DUAL) w1 = *(const float4*)&Ws1[kk][tcol*4];
      #pragma unroll
      for (int i=0;i<8;i++){
        float a = As[trow*8+i][kk];
        aC[i][0] += a*w0.x; aC[i][1] += a*w0.y; aC[i][2] += a*w0.z; aC[i][3] += a*w0.w;
        if (DUAL){ aL[i][0]+=a*w1.x; aL[i][1]+=a*w1.y; aL[i][2]+=a*w1.z; aL[i][3]+=a*w1.w; }
      }
    }
    __syncthreads();
  }
  float4 bb0 = *(const float4*)&b0[tcol*4];
  float4 bb1 = make_float4(0.f,0.f,0.f,0.f);
  if (DUAL) bb1 = *(const float4*)&b1[tcol*4];
  #pragma unroll
  for (int i=0;i<8;i++){
    int gn = n0 + trow*8 + i;
    if (gn >= n) continue;
    if (DUAL){
      float dn = dinv[gn]; float snm = dn*dn;
      ushort4 xb;
      xb.x = f2bf(aC[i][0]); xb.y = f2bf(aC[i][1]); xb.z = f2bf(aC[i][2]); xb.w = f2bf(aC[i][3]);
      *(ushort4*)&O0b[gn*HID + tcol*4] = xb;
      float4 bs;
      bs.x = aL[i][0] + bb0.x + bb1.x + aC[i][0]*snm;
      bs.y = aL[i][1] + bb0.y + bb1.y + aC[i][1]*snm;
      bs.z = aL[i][2] + bb0.z + bb1.z + aC[i][2]*snm;
      bs.w = aL[i][3] + bb0.w + bb1.w + aC[i][3]*snm;
      *(float4*)&O1[gn*HID + tcol*4] = bs;
    } else {
      float4 xo;
      xo.x = eluf(aC[i][0] + bb0.x);
      xo.y = eluf(aC[i][1] + bb0.y);
      xo.z = eluf(aC[i][2] + bb0.z);
      xo.w = eluf(aC[i][3] + bb0.w);
      *(float4*)&O0f[gn*HID + tcol*4] = xo;
    }
  }
}

// one wave per node: gather bf16 xw rows of in-neighbors (unroll 4 for MLP),
// fuse elu + residual acc update. Lane handles elems {2*lane, 2*lane+1}.
__global__ __launch_bounds__(256) void k_agg(const unsigned* __restrict__ xwb, const float* __restrict__ base,
    float* __restrict__ acc, const int* __restrict__ rowptr, const int* __restrict__ rowend,
    const int* __restrict__ csrc, const float* __restrict__ cw, int n)
{
  int wid = threadIdx.x>>6, lane = threadIdx.x & 63;
  int node = __builtin_amdgcn_readfirstlane(blockIdx.x*4 + wid);
  if (node>=n) return;
  int s = rowptr[node], e = rowend[node];
  float s0=0.f, s1=0.f;
  int p = s;
  for (; p+4<=e; p+=4){
    int u0=csrc[p], u1=csrc[p+1], u2=csrc[p+2], u3=csrc[p+3];
    float w0=cw[p], w1=cw[p+1], w2=cw[p+2], w3=cw[p+3];
    unsigned a0 = xwb[u0*64 + lane];
    unsigned a1 = xwb[u1*64 + lane];
    unsigned a2 = xwb[u2*64 + lane];
    unsigned a3 = xwb[u3*64 + lane];
    s0 += w0*bflo(a0); s1 += w0*bfhi(a0);
    s0 += w1*bflo(a1); s1 += w1*bfhi(a1);
    s0 += w2*bflo(a2); s1 += w2*bfhi(a2);
    s0 += w3*bflo(a3); s1 += w3*bfhi(a3);
  }
  for (; p<e; p++){
    int u = csrc[p]; float w = cw[p];
    unsigned a = xwb[u*64 + lane];
    s0 += w*bflo(a); s1 += w*bfhi(a);
  }
  float2 b = *(const float2*)&base[node*HID + lane*2];
  float x0 = eluf(b.x + s0), x1 = eluf(b.y + s1);
  float2 a = *(float2*)&acc[node*HID + lane*2];
  a.x += x0; a.y += x1;
  *(float2*)&acc[node*HID + lane*2] = a;
}

static __device__ __forceinline__ int lowerb(const int* a, int nn, int key){
  int lo=0, hi=nn;
  while (lo<hi){ int m=(lo+hi)>>1; if (a[m]<key) lo=m+1; else hi=m; }
  return lo;
}

// deterministic 2-stage pooling, stage 1: G*POOL_S blocks, fixed row partition
__global__ __launch_bounds__(128) void k_pool_part(const float* __restrict__ x, const int* __restrict__ batch,
                                                   float* __restrict__ part, int n){
  int g = blockIdx.x / POOL_S, s = blockIdx.x % POOL_S;
  int d = threadIdx.x;
  int lo = lowerb(batch, n, g), hi = lowerb(batch, n, g+1);
  float sum = 0.f;
  for (int r = lo + s; r < hi; r += POOL_S) sum += x[r*HID + d];
  part[blockIdx.x*HID + d] = sum;
}

// stage 2 fused into pred: fixed-order reduce of POOL_S partials, then GEMV
__global__ __launch_bounds__(128) void k_pred(const float* __restrict__ part, const float* __restrict__ W,
                                              const float* __restrict__ b, float* __restrict__ out, int G){
  __shared__ float pr[HID];
  int g = blockIdx.x, o = threadIdx.x;
  float s = 0.f;
  #pragma unroll
  for (int q=0;q<POOL_S;q++) s += part[(g*POOL_S+q)*HID + o];
  pr[o] = s;
  __syncthreads();
  float acc = b[o];
  #pragma unroll 8
  for (int k=0;k<HID;k++) acc += pr[k]*W[k*HID+o];
  out[g*HID+o] = acc*0.1f;
}

extern "C" void kernel_launch(void* const* d_in, const int* in_sizes, int n_in,
                              void* d_out, int out_size, void* d_ws, size_t ws_size,
                              hipStream_t stream)
{
  const int*   x_idx  = (const int*)d_in[0];
  const int*   eidx   = (const int*)d_in[1];
  const int*   batch  = (const int*)d_in[2];
  const float* emb    = (const float*)d_in[3];
  const float* convW  = (const float*)d_in[4];
  const float* convb  = (const float*)d_in[5];
  const float* linW   = (const float*)d_in[6];
  const float* linb   = (const float*)d_in[7];
  const float* mlpW   = (const float*)d_in[8];
  const float* mlpb   = (const float*)d_in[9];
  const float* predW  = (const float*)d_in[10];
  const float* predb  = (const float*)d_in[11];
  float* out = (float*)d_out;
  int N = in_sizes[0];
  int E = in_sizes[1]/2;
  int G = out_size / 128;   // OUT = 128

  char* p = (char*)d_ws;
  auto alloc = [&](size_t bytes)->char*{ char* q = p; p += (bytes + 255) & ~(size_t)255; return q; };
  int*   deg    = (int*)  alloc((size_t)N*4);
  int*   rowptr = (int*)  alloc((size_t)N*4);
  int*   cursor = (int*)  alloc((size_t)N*4);
  int*   bsums  = (int*)  alloc(4096);
  float* dinv   = (float*)alloc((size_t)N*4);
  int*   csrc   = (int*)  alloc((size_t)E*4);
  float* cw     = (float*)alloc((size_t)E*4);
  float* acc    = (float*)alloc((size_t)N*HID*4);
  float* xw     = (float*)alloc((size_t)N*HID*4);  // fp32 for MLP out; bf16 alias for layers
  float* basev  = (float*)alloc((size_t)N*HID*4);
  float* part   = (float*)alloc((size_t)G*POOL_S*HID*4);
  if ((size_t)(p - (char*)d_ws) > ws_size) return; // ws too small: leave poison -> loud failure

  unsigned short* xwb = (unsigned short*)xw;

  const int* src = eidx;
  const int* dst = eidx + E;

  hipMemsetAsync(deg, 0, (size_t)N*4, stream);
  k_hist<<<(E+255)/256,256,0,stream>>>(dst, deg, E);
  int nb = (N+1023)/1024;
  k_scan_local<<<nb,256,0,stream>>>(deg, rowptr, bsums, N);
  k_scan_bsums<<<1,1,0,stream>>>(bsums, nb);
  k_finalize<<<(N+255)/256,256,0,stream>>>(deg, rowptr, bsums, cursor, dinv, N);
  k_fill<<<(E+255)/256,256,0,stream>>>(src, dst, cursor, dinv, csrc, cw, E);
  k_init_acc<<<(N*32+255)/256,256,0,stream>>>(emb, x_idx, acc, N);

  int gblk = (N+63)/64;
  for (int l=0;l<3;l++){
    k_gemm<true><<<gblk,256,0,stream>>>(acc, convW + (size_t)l*HID*HID, linW + (size_t)l*HID*HID,
                                        convb + l*HID, linb + l*HID, dinv, xwb, nullptr, basev, N);
    k_agg<<<(N+3)/4,256,0,stream>>>((const unsigned*)xwb, basev, acc, rowptr, cursor, csrc, cw, N);
  }
  k_gemm<false><<<gblk,256,0,stream>>>(acc, mlpW, nullptr, mlpb, nullptr, nullptr, nullptr, xw, nullptr, N);
  k_pool_part<<<G*POOL_S,128,0,stream>>>(xw, batch, part, N);
  k_pred<<<G,128,0,stream>>>(part, predW, predb, out, G);
}

// Round 5
// 355.874 us; speedup vs baseline: 1.9666x; 1.2614x over previous
//
#include <hip/hip_runtime.h>
#include <math.h>

#define HID 128
#define POOL_S 8

typedef __attribute__((ext_vector_type(8))) short bf16x8;
typedef __attribute__((ext_vector_type(4))) float f32x4;

static __device__ __forceinline__ float eluf(float x){ return x > 0.f ? x : expm1f(x); }

// round-to-nearest-even f32 -> bf16 bits
static __device__ __forceinline__ unsigned short f2bf(float f){
  unsigned u = __builtin_bit_cast(unsigned, f);
  u += 0x7fffu + ((u >> 16) & 1u);
  return (unsigned short)(u >> 16);
}
static __device__ __forceinline__ float bf2f(unsigned short h){
  return __builtin_bit_cast(float, (unsigned)h << 16);
}
static __device__ __forceinline__ float bflo(unsigned u){ return __builtin_bit_cast(float, u << 16); }
static __device__ __forceinline__ float bfhi(unsigned u){ return __builtin_bit_cast(float, u & 0xffff0000u); }

__global__ __launch_bounds__(256) void k_hist(const int* __restrict__ dst, int* __restrict__ deg, int E){
  int e = blockIdx.x*256 + threadIdx.x;
  if (e < E) atomicAdd(&deg[dst[e]], 1);
}

__global__ __launch_bounds__(256) void k_scan_local(const int* __restrict__ deg, int* __restrict__ excl,
                                                    int* __restrict__ bsums, int n){
  __shared__ int ts[256];
  int t = threadIdx.x;
  int base = blockIdx.x*1024;
  int v[4]; int s = 0;
  #pragma unroll
  for (int j=0;j<4;j++){ int i = base + t*4 + j; v[j] = (i<n)?deg[i]:0; s += v[j]; }
  ts[t]=s; __syncthreads();
  for (int off=1; off<256; off<<=1){
    int x = (t>=off)?ts[t-off]:0; __syncthreads();
    ts[t]+=x; __syncthreads();
  }
  int excl_t = ts[t]-s;
  if (t==255) bsums[blockIdx.x]=ts[255];
  int run = excl_t;
  #pragma unroll
  for (int j=0;j<4;j++){ int i = base+t*4+j; if (i<n) excl[i]=run; run+=v[j]; }
}

__global__ void k_scan_bsums(int* bsums, int nb){
  int run=0;
  for (int i=0;i<nb;i++){ int x=bsums[i]; bsums[i]=run; run+=x; }
}

__global__ __launch_bounds__(256) void k_finalize(const int* __restrict__ deg, int* __restrict__ rowptr,
                                                  const int* __restrict__ bsums, int* __restrict__ cursor,
                                                  float* __restrict__ dinv, int n){
  int i = blockIdx.x*256+threadIdx.x;
  if (i<n){
    int r = rowptr[i] + bsums[i>>10];
    rowptr[i]=r; cursor[i]=r;
    dinv[i] = rsqrtf((float)deg[i] + 1.0f);
  }
}

__global__ __launch_bounds__(256) void k_fill(const int* __restrict__ src, const int* __restrict__ dst,
                                              int* __restrict__ cursor, const float* __restrict__ dinv,
                                              int* __restrict__ csrc, float* __restrict__ cw, int E){
  int e = blockIdx.x*256+threadIdx.x;
  if (e<E){
    int s = src[e], d = dst[e];
    int p = atomicAdd(&cursor[d],1);
    csrc[p]=s; cw[p]=dinv[s]*dinv[d];
  }
}

__global__ __launch_bounds__(256) void k_init_acc(const float* __restrict__ emb, const int* __restrict__ xidx,
                                                  float* __restrict__ acc, int n){
  int i = blockIdx.x*256+threadIdx.x;
  int total = n*32;
  if (i<total){
    int nn = i>>5, q = i&31;
    ((float4*)acc)[i] = ((const float4*)emb)[xidx[nn]*32+q];
  }
}

// Pre-split 7 weight matrices (conv0..2, lin0..2, mlp) into hi/lo bf16 in
// MFMA B-frag-friendly layout: wsplit[(((mat*2+hilo)*4+ks)*8+ct)*1024 + (kg*16+c)*8 + j]
// holds W[ks*32 + kg*8 + j][ct*16 + c].
__global__ __launch_bounds__(256) void k_split_w(const float* __restrict__ convW,
    const float* __restrict__ linW, const float* __restrict__ mlpW,
    unsigned short* __restrict__ wsplit){
  int idx = blockIdx.x*256 + threadIdx.x;   // 7*16384 total
  int mat = idx >> 14, rem = idx & 16383;
  int k = rem >> 7, col = rem & 127;
  const float* Wp = (mat < 3) ? (convW + (size_t)mat*16384)
                  : (mat < 6) ? (linW + (size_t)(mat-3)*16384)
                              : mlpW;
  float w = Wp[k*HID + col];
  unsigned short hi = f2bf(w);
  unsigned short lo = f2bf(w - bf2f(hi));
  int ks = k>>5, kg = (k>>3)&3, j = k&7, ct = col>>4, c = col&15;
  size_t base = (((size_t)(mat*2)*4 + ks)*8 + ct)*1024 + (size_t)(kg*16 + c)*8 + j;
  wsplit[base] = hi;
  wsplit[base + 32768] = lo;   // hilo stride = 4*8*1024
}

// MFMA split-GEMM: BM=128 rows/block, 8 waves (512 thr), wave = coltile ct (16 cols).
// 3x-bf16 split: acc += ah@wh + al@wh + ah@wl  (near-fp32 accuracy).
// DUAL: O0b = bf16(A@W0); O1 = A@W1 + b0 + b1 + (A@W0)*dinv^2 (fp32)
// !DUAL: O0f = elu(A@W0 + b0) (fp32)
template<bool DUAL>
__global__ __launch_bounds__(512) void k_mm(
    const float* __restrict__ A, const unsigned short* __restrict__ wsplit,
    int mat0, int mat1,
    const float* __restrict__ b0, const float* __restrict__ b1,
    const float* __restrict__ dinv,
    unsigned short* __restrict__ O0b, float* __restrict__ O0f,
    float* __restrict__ O1, int n)
{
  __shared__ unsigned short ahi[4096];  // [mt(8)][kg(4)][r16(16)][j(8)]
  __shared__ unsigned short alo[4096];
  int tid = threadIdx.x;
  int lane = tid & 63;
  int wv = tid >> 6;            // wave id == coltile ct
  int n0 = blockIdx.x * 128;

  f32x4 acc0[8]; f32x4 acc1[DUAL?8:1];
  #pragma unroll
  for (int mt=0; mt<8; ++mt){ acc0[mt] = (f32x4)0.f; if (DUAL) acc1[mt] = (f32x4)0.f; }

  // staging assignment: thread -> (row, kg)
  int srow = tid >> 2;          // 0..127
  int skg  = tid & 3;
  bool svalid = (n0 + srow) < n;
  const float* aptr = A + (size_t)(n0 + srow)*HID + skg*8;
  int selem = ((srow>>4)*4 + skg)*128 + (srow&15)*8;

  // frag lane offsets (elements)
  int flane = ((lane>>4)*16 + (lane&15))*8;   // A LDS (+mt*512) and W-split lane offset

  size_t wbase0 = (((size_t)(mat0*2)*4)*8 + wv)*1024 + flane;     // + ks*8192
  size_t wbase1 = DUAL ? ((((size_t)(mat1*2)*4)*8 + wv)*1024 + flane) : 0;

  for (int ks=0; ks<4; ++ks){
    float4 v0 = make_float4(0.f,0.f,0.f,0.f), v1 = v0;
    if (svalid){
      v0 = *(const float4*)(aptr + ks*32);
      v1 = *(const float4*)(aptr + ks*32 + 4);
    }
    float f[8] = {v0.x,v0.y,v0.z,v0.w,v1.x,v1.y,v1.z,v1.w};
    bf16x8 ph, pl;
    #pragma unroll
    for (int j=0;j<8;j++){
      unsigned short h = f2bf(f[j]);
      unsigned short l = f2bf(f[j] - bf2f(h));
      ph[j] = (short)h; pl[j] = (short)l;
    }
    __syncthreads();                 // prev-iteration reads done
    *(bf16x8*)&ahi[selem] = ph;
    *(bf16x8*)&alo[selem] = pl;
    __syncthreads();                 // staging visible

    bf16x8 ah[8], al[8];
    #pragma unroll
    for (int mt=0; mt<8; ++mt){
      ah[mt] = *(const bf16x8*)&ahi[mt*512 + flane];
      al[mt] = *(const bf16x8*)&alo[mt*512 + flane];
    }
    {
      bf16x8 wh = *(const bf16x8*)&wsplit[wbase0 + (size_t)ks*8192];
      bf16x8 wl = *(const bf16x8*)&wsplit[wbase0 + (size_t)ks*8192 + 32768];
      #pragma unroll
      for (int mt=0; mt<8; ++mt){
        acc0[mt] = __builtin_amdgcn_mfma_f32_16x16x32_bf16(ah[mt], wh, acc0[mt], 0,0,0);
        acc0[mt] = __builtin_amdgcn_mfma_f32_16x16x32_bf16(al[mt], wh, acc0[mt], 0,0,0);
        acc0[mt] = __builtin_amdgcn_mfma_f32_16x16x32_bf16(ah[mt], wl, acc0[mt], 0,0,0);
      }
    }
    if (DUAL){
      bf16x8 wh = *(const bf16x8*)&wsplit[wbase1 + (size_t)ks*8192];
      bf16x8 wl = *(const bf16x8*)&wsplit[wbase1 + (size_t)ks*8192 + 32768];
      #pragma unroll
      for (int mt=0; mt<8; ++mt){
        acc1[mt] = __builtin_amdgcn_mfma_f32_16x16x32_bf16(ah[mt], wh, acc1[mt], 0,0,0);
        acc1[mt] = __builtin_amdgcn_mfma_f32_16x16x32_bf16(al[mt], wh, acc1[mt], 0,0,0);
        acc1[mt] = __builtin_amdgcn_mfma_f32_16x16x32_bf16(ah[mt], wl, acc1[mt], 0,0,0);
      }
    }
  }

  // epilogue: D[i][c]: i=(lane>>4)*4+r, c=lane&15
  int col = wv*16 + (lane&15);
  float bb0 = b0[col];
  float bb1 = DUAL ? b1[col] : 0.f;
  #pragma unroll
  for (int mt=0; mt<8; ++mt){
    #pragma unroll
    for (int r=0; r<4; ++r){
      int gn = n0 + mt*16 + (lane>>4)*4 + r;
      if (gn >= n) continue;
      float xc = acc0[mt][r];
      if (DUAL){
        float dn = dinv[gn];
        O0b[(size_t)gn*HID + col] = f2bf(xc);
        O1[(size_t)gn*HID + col] = acc1[mt][r] + bb0 + bb1 + xc*dn*dn;
      } else {
        O0f[(size_t)gn*HID + col] = eluf(xc + bb0);
      }
    }
  }
}

// one wave per node: gather bf16 xw rows of in-neighbors (unroll 4),
// fuse elu + residual acc update. Lane handles elems {2*lane, 2*lane+1}.
__global__ __launch_bounds__(256) void k_agg(const unsigned* __restrict__ xwb, const float* __restrict__ base,
    float* __restrict__ acc, const int* __restrict__ rowptr, const int* __restrict__ rowend,
    const int* __restrict__ csrc, const float* __restrict__ cw, int n)
{
  int wid = threadIdx.x>>6, lane = threadIdx.x & 63;
  int node = __builtin_amdgcn_readfirstlane(blockIdx.x*4 + wid);
  if (node>=n) return;
  int s = rowptr[node], e = rowend[node];
  float s0=0.f, s1=0.f;
  int p = s;
  for (; p+4<=e; p+=4){
    int u0=csrc[p], u1=csrc[p+1], u2=csrc[p+2], u3=csrc[p+3];
    float w0=cw[p], w1=cw[p+1], w2=cw[p+2], w3=cw[p+3];
    unsigned a0 = xwb[u0*64 + lane];
    unsigned a1 = xwb[u1*64 + lane];
    unsigned a2 = xwb[u2*64 + lane];
    unsigned a3 = xwb[u3*64 + lane];
    s0 += w0*bflo(a0); s1 += w0*bfhi(a0);
    s0 += w1*bflo(a1); s1 += w1*bfhi(a1);
    s0 += w2*bflo(a2); s1 += w2*bfhi(a2);
    s0 += w3*bflo(a3); s1 += w3*bfhi(a3);
  }
  for (; p<e; p++){
    int u = csrc[p]; float w = cw[p];
    unsigned a = xwb[u*64 + lane];
    s0 += w*bflo(a); s1 += w*bfhi(a);
  }
  float2 b = *(const float2*)&base[node*HID + lane*2];
  float x0 = eluf(b.x + s0), x1 = eluf(b.y + s1);
  float2 a = *(float2*)&acc[node*HID + lane*2];
  a.x += x0; a.y += x1;
  *(float2*)&acc[node*HID + lane*2] = a;
}

static __device__ __forceinline__ int lowerb(const int* a, int nn, int key){
  int lo=0, hi=nn;
  while (lo<hi){ int m=(lo+hi)>>1; if (a[m]<key) lo=m+1; else hi=m; }
  return lo;
}

__global__ __launch_bounds__(128) void k_pool_part(const float* __restrict__ x, const int* __restrict__ batch,
                                                   float* __restrict__ part, int n){
  int g = blockIdx.x / POOL_S, s = blockIdx.x % POOL_S;
  int d = threadIdx.x;
  int lo = lowerb(batch, n, g), hi = lowerb(batch, n, g+1);
  float sum = 0.f;
  for (int r = lo + s; r < hi; r += POOL_S) sum += x[r*HID + d];
  part[blockIdx.x*HID + d] = sum;
}

__global__ __launch_bounds__(128) void k_pred(const float* __restrict__ part, const float* __restrict__ W,
                                              const float* __restrict__ b, float* __restrict__ out, int G){
  __shared__ float pr[HID];
  int g = blockIdx.x, o = threadIdx.x;
  float s = 0.f;
  #pragma unroll
  for (int q=0;q<POOL_S;q++) s += part[(g*POOL_S+q)*HID + o];
  pr[o] = s;
  __syncthreads();
  float acc = b[o];
  #pragma unroll 8
  for (int k=0;k<HID;k++) acc += pr[k]*W[k*HID+o];
  out[g*HID+o] = acc*0.1f;
}

extern "C" void kernel_launch(void* const* d_in, const int* in_sizes, int n_in,
                              void* d_out, int out_size, void* d_ws, size_t ws_size,
                              hipStream_t stream)
{
  const int*   x_idx  = (const int*)d_in[0];
  const int*   eidx   = (const int*)d_in[1];
  const int*   batch  = (const int*)d_in[2];
  const float* emb    = (const float*)d_in[3];
  const float* convW  = (const float*)d_in[4];
  const float* convb  = (const float*)d_in[5];
  const float* linW   = (const float*)d_in[6];
  const float* linb   = (const float*)d_in[7];
  const float* mlpW   = (const float*)d_in[8];
  const float* mlpb   = (const float*)d_in[9];
  const float* predW  = (const float*)d_in[10];
  const float* predb  = (const float*)d_in[11];
  float* out = (float*)d_out;
  int N = in_sizes[0];
  int E = in_sizes[1]/2;
  int G = out_size / 128;   // OUT = 128

  char* p = (char*)d_ws;
  auto alloc = [&](size_t bytes)->char*{ char* q = p; p += (bytes + 255) & ~(size_t)255; return q; };
  int*   deg    = (int*)  alloc((size_t)N*4);
  int*   rowptr = (int*)  alloc((size_t)N*4);
  int*   cursor = (int*)  alloc((size_t)N*4);
  int*   bsums  = (int*)  alloc(4096);
  float* dinv   = (float*)alloc((size_t)N*4);
  int*   csrc   = (int*)  alloc((size_t)E*4);
  float* cw     = (float*)alloc((size_t)E*4);
  float* acc    = (float*)alloc((size_t)N*HID*4);
  float* xw     = (float*)alloc((size_t)N*HID*4);  // fp32 for MLP out; bf16 alias for layers
  float* basev  = (float*)alloc((size_t)N*HID*4);
  float* part   = (float*)alloc((size_t)G*POOL_S*HID*4);
  unsigned short* wsplit = (unsigned short*)alloc((size_t)7*2*16384*2);
  if ((size_t)(p - (char*)d_ws) > ws_size) return; // ws too small: leave poison -> loud failure

  unsigned short* xwb = (unsigned short*)xw;

  const int* src = eidx;
  const int* dst = eidx + E;

  hipMemsetAsync(deg, 0, (size_t)N*4, stream);
  k_split_w<<<(7*16384)/256,256,0,stream>>>(convW, linW, mlpW, wsplit);
  k_hist<<<(E+255)/256,256,0,stream>>>(dst, deg, E);
  int nb = (N+1023)/1024;
  k_scan_local<<<nb,256,0,stream>>>(deg, rowptr, bsums, N);
  k_scan_bsums<<<1,1,0,stream>>>(bsums, nb);
  k_finalize<<<(N+255)/256,256,0,stream>>>(deg, rowptr, bsums, cursor, dinv, N);
  k_fill<<<(E+255)/256,256,0,stream>>>(src, dst, cursor, dinv, csrc, cw, E);
  k_init_acc<<<(N*32+255)/256,256,0,stream>>>(emb, x_idx, acc, N);

  int mblk = (N+127)/128;
  for (int l=0;l<3;l++){
    k_mm<true><<<mblk,512,0,stream>>>(acc, wsplit, l, 3+l,
                                      convb + l*HID, linb + l*HID, dinv,
                                      xwb, nullptr, basev, N);
    k_agg<<<(N+3)/4,256,0,stream>>>((const unsigned*)xwb, basev, acc, rowptr, cursor, csrc, cw, N);
  }
  k_mm<false><<<mblk,512,0,stream>>>(acc, wsplit, 6, 6, mlpb, nullptr, nullptr,
                                     nullptr, xw, nullptr, N);
  k_pool_part<<<G*POOL_S,128,0,stream>>>(xw, batch, part, N);
  k_pred<<<G,128,0,stream>>>(part, predW, predb, out, G);
}